// Round 1
// baseline (85167.206 us; speedup 1.0000x reference)
//
#include <hip/hip_runtime.h>

#define NNODES 50000
#define NEDGES 800000
#define HDIM 128
#define CDIM 10
#define LNUM 3
#define ONUM 2
#define KHOPS 10
#define GNUM 128
#define EPSBN 1e-5f

// Generic row-block GEMM: out[N,Hout] = [A0 | A1] @ W + bias, optional BN (g,be), relu.
// Optionally also writes hid = fw0[0] * out (pre-used for HiGCN_prop init term).
// Block = 128 threads (one per output col), 8 rows per block, A rows staged in LDS
// (broadcast reads, conflict-free), W reads coalesced across threads.
__global__ void gemm_rows(const float* __restrict__ A0, const float* __restrict__ A1,
                          const float* __restrict__ W, const float* __restrict__ bias,
                          const float* __restrict__ g, const float* __restrict__ be,
                          const float* __restrict__ fw0,
                          float* __restrict__ out, float* __restrict__ hid,
                          int N, int Hout, int relu)
{
    const int Kdim = A1 ? 2 * HDIM : HDIM;
    __shared__ float a[8][2 * HDIM];
    const int row0 = blockIdx.x * 8;
    const int tid  = threadIdx.x;

    for (int r = 0; r < 8; ++r) {
        int row = row0 + r;
        for (int k = tid; k < Kdim; k += 128) {
            float v = 0.f;
            if (row < N)
                v = (k < HDIM) ? A0[(size_t)row * HDIM + k]
                               : A1[(size_t)row * HDIM + (k - HDIM)];
            a[r][k] = v;
        }
    }
    __syncthreads();

    if (tid < Hout) {
        float acc[8];
#pragma unroll
        for (int r = 0; r < 8; ++r) acc[r] = 0.f;
        for (int k = 0; k < Kdim; ++k) {
            float wv = W[(size_t)k * Hout + tid];
#pragma unroll
            for (int r = 0; r < 8; ++r) acc[r] += a[r][k] * wv;
        }
        const float bs = bias[tid];
        float scale = 1.f, beta = 0.f;
        if (g) { scale = g[tid] * rsqrtf(1.f + EPSBN); beta = be[tid]; }
        const float f0 = fw0 ? fw0[0] : 0.f;
        for (int r = 0; r < 8; ++r) {
            int row = row0 + r;
            if (row >= N) break;
            float v = acc[r] + bs;
            if (g) v = v * scale + beta;
            if (relu) v = fmaxf(v, 0.f);
            out[(size_t)row * Hout + tid] = v;
            if (hid) hid[(size_t)row * Hout + tid] = f0 * v;
        }
    }
}

// zout[dst] += w * zin[src]; 32 threads per edge, float4 per thread.
__global__ void spmm_kernel(const int* __restrict__ dst, const int* __restrict__ src,
                            const float* __restrict__ w, const float* __restrict__ zin,
                            float* __restrict__ zout)
{
    unsigned t = blockIdx.x * blockDim.x + threadIdx.x;
    unsigned e = t >> 5;
    if (e >= NEDGES) return;
    unsigned lane = t & 31;
    int s = src[e], d = dst[e];
    float wt = w[e];
    const float4 v = ((const float4*)(zin + (size_t)s * HDIM))[lane];
    float* o = zout + (size_t)d * HDIM + (size_t)lane * 4;
    atomicAdd(o + 0, wt * v.x);
    atomicAdd(o + 1, wt * v.y);
    atomicAdd(o + 2, wt * v.z);
    atomicAdd(o + 3, wt * v.w);
}

// hid += fwp[0] * z; also zeroes `tozero` (next hop's spmm output buffer).
__global__ void axpy_zero(float4* __restrict__ hid, const float4* __restrict__ z,
                          const float* __restrict__ fwp, float4* __restrict__ tozero,
                          int n4)
{
    int i = blockIdx.x * blockDim.x + threadIdx.x;
    if (i >= n4) return;
    const float c = fwp[0];
    float4 h = hid[i];
    const float4 zz = z[i];
    h.x += c * zz.x; h.y += c * zz.y; h.z += c * zz.z; h.w += c * zz.w;
    hid[i] = h;
    tozero[i] = make_float4(0.f, 0.f, 0.f, 0.f);
}

// pool[batch[i]] += h[i]
__global__ void pool_kernel(const float* __restrict__ h, const int* __restrict__ batch,
                            float* __restrict__ pool)
{
    unsigned t = blockIdx.x * blockDim.x + threadIdx.x;
    unsigned i = t >> 5;
    if (i >= NNODES) return;
    unsigned lane = t & 31;
    int b = batch[i];
    const float4 v = ((const float4*)(h + (size_t)i * HDIM))[lane];
    float* o = pool + (size_t)b * HDIM + (size_t)lane * 4;
    atomicAdd(o + 0, v.x);
    atomicAdd(o + 1, v.y);
    atomicAdd(o + 2, v.z);
    atomicAdd(o + 3, v.w);
}

extern "C" void kernel_launch(void* const* d_in, const int* in_sizes, int n_in,
                              void* d_out, int out_size, void* d_ws, size_t ws_size,
                              hipStream_t stream)
{
    const float* x     = (const float*)d_in[0];
    const int*   ei    = (const int*)  d_in[1];   // [O,2,E]: [o,0,:]=dst, [o,1,:]=src
    const float* ew    = (const float*)d_in[2];   // [O,E]
    const int*   batch = (const int*)  d_in[3];
    const float* W_in  = (const float*)d_in[4];   // [L,O,F,H]
    const float* b_in  = (const float*)d_in[5];   // [L,O,H]
    const float* fW    = (const float*)d_in[6];   // [L,O,K+1]
    const float* W_out = (const float*)d_in[7];   // [L,2H,H]
    const float* b_out = (const float*)d_in[8];   // [L,H]
    const float* Wn1   = (const float*)d_in[9];
    const float* bn1   = (const float*)d_in[10];
    const float* g1    = (const float*)d_in[11];
    const float* be1   = (const float*)d_in[12];
    const float* Wn2   = (const float*)d_in[13];
    const float* bn2   = (const float*)d_in[14];
    const float* g2    = (const float*)d_in[15];
    const float* be2   = (const float*)d_in[16];
    const float* W1    = (const float*)d_in[17];
    const float* b1    = (const float*)d_in[18];
    const float* W2    = (const float*)d_in[19];
    const float* b2    = (const float*)d_in[20];
    float* out = (float*)d_out;

    const size_t NH = (size_t)NNODES * HDIM;   // 6.4M floats
    float* ws    = (float*)d_ws;
    float* f_h   = ws;
    float* f_zA  = ws + NH;
    float* f_zB  = ws + 2 * NH;
    float* f_h0  = ws + 3 * NH;
    float* f_h1  = ws + 4 * NH;
    float* f_pl  = ws + 5 * NH;                 // [G,H]
    float* f_pl2 = f_pl + (size_t)GNUM * HDIM;  // [G,H]

    const int gemm_grid = (NNODES + 7) / 8;        // 6250
    const int spmm_grid = (NEDGES * 32) / 256;     // 100000
    const int n4        = (int)(NH / 4);           // 1.6M
    const int axpy_grid = (n4 + 255) / 256;        // 6250

    const float* curH = x;
    for (int l = 0; l < LNUM; ++l) {
        for (int o = 0; o < ONUM; ++o) {
            float* hid = (o == 0) ? f_h0 : f_h1;
            const int lo = l * ONUM + o;
            // z = h @ W_in + b_in ; hid = fW[0]*z
            gemm_rows<<<gemm_grid, 128, 0, stream>>>(
                curH, nullptr,
                W_in + (size_t)lo * HDIM * HDIM, b_in + (size_t)lo * HDIM,
                nullptr, nullptr, fW + (size_t)lo * (KHOPS + 1),
                f_zA, hid, NNODES, HDIM, 0);
            hipMemsetAsync(f_zB, 0, NH * sizeof(float), stream);

            const int*   dstp = ei + (size_t)o * 2 * NEDGES;
            const int*   srcp = dstp + NEDGES;
            const float* wp   = ew + (size_t)o * NEDGES;
            float *za = f_zA, *zb = f_zB;
            for (int k = 0; k < KHOPS; ++k) {
                spmm_kernel<<<spmm_grid, 256, 0, stream>>>(dstp, srcp, wp, za, zb);
                axpy_zero<<<axpy_grid, 256, 0, stream>>>(
                    (float4*)hid, (float4*)zb,
                    fW + (size_t)lo * (KHOPS + 1) + (k + 1),
                    (float4*)za, n4);
                float* tmp = za; za = zb; zb = tmp;
            }
        }
        // xc = [hid0|hid1] @ W_out + b_out
        gemm_rows<<<gemm_grid, 128, 0, stream>>>(
            f_h0, f_h1, W_out + (size_t)l * 2 * HDIM * HDIM, b_out + (size_t)l * HDIM,
            nullptr, nullptr, nullptr, f_zA, nullptr, NNODES, HDIM, 0);
        // xc = relu(bn(xc @ Wn1 + bn1))
        gemm_rows<<<gemm_grid, 128, 0, stream>>>(
            f_zA, nullptr, Wn1 + (size_t)l * HDIM * HDIM, bn1 + (size_t)l * HDIM,
            g1 + (size_t)l * HDIM, be1 + (size_t)l * HDIM, nullptr,
            f_zB, nullptr, NNODES, HDIM, 1);
        // h = relu(bn(xc @ Wn2 + bn2))
        gemm_rows<<<gemm_grid, 128, 0, stream>>>(
            f_zB, nullptr, Wn2 + (size_t)l * HDIM * HDIM, bn2 + (size_t)l * HDIM,
            g2 + (size_t)l * HDIM, be2 + (size_t)l * HDIM, nullptr,
            f_h, nullptr, NNODES, HDIM, 1);
        curH = f_h;
    }

    // global_add_pool
    hipMemsetAsync(f_pl, 0, (size_t)GNUM * HDIM * sizeof(float), stream);
    pool_kernel<<<(NNODES * 32 + 255) / 256, 256, 0, stream>>>(curH, batch, f_pl);
    // p = relu(p @ W1 + b1)
    gemm_rows<<<(GNUM + 7) / 8, 128, 0, stream>>>(
        f_pl, nullptr, W1, b1, nullptr, nullptr, nullptr, f_pl2, nullptr, GNUM, HDIM, 1);
    // out = p @ W2 + b2
    gemm_rows<<<(GNUM + 7) / 8, 128, 0, stream>>>(
        f_pl2, nullptr, W2, b2, nullptr, nullptr, nullptr, out, nullptr, GNUM, CDIM, 0);
}

// Round 2
// 5421.697 us; speedup vs baseline: 15.7086x; 15.7086x over previous
//
#include <hip/hip_runtime.h>

#define NNODES 50000
#define NEDGES 800000
#define HDIM 128
#define CDIM 10
#define LNUM 3
#define ONUM 2
#define KHOPS 10
#define GNUM 128
#define EPSBN 1e-5f

// Generic row-block GEMM: out[N,Hout] = [A0 | A1] @ W + bias, optional BN (g,be), relu.
// Optionally also writes hid = fw0[0] * out. Per-block: rows staged in LDS first
// (sync), then written — so hid may alias A0 row-for-row (in-place safe).
__global__ void gemm_rows(const float* __restrict__ A0, const float* __restrict__ A1,
                          const float* __restrict__ W, const float* __restrict__ bias,
                          const float* __restrict__ g, const float* __restrict__ be,
                          const float* __restrict__ fw0,
                          float* __restrict__ out, float* __restrict__ hid,
                          int N, int Hout, int relu)
{
    const int Kdim = A1 ? 2 * HDIM : HDIM;
    __shared__ float a[8][2 * HDIM];
    const int row0 = blockIdx.x * 8;
    const int tid  = threadIdx.x;

    for (int r = 0; r < 8; ++r) {
        int row = row0 + r;
        for (int k = tid; k < Kdim; k += 128) {
            float v = 0.f;
            if (row < N)
                v = (k < HDIM) ? A0[(size_t)row * HDIM + k]
                               : A1[(size_t)row * HDIM + (k - HDIM)];
            a[r][k] = v;
        }
    }
    __syncthreads();

    if (tid < Hout) {
        float acc[8];
#pragma unroll
        for (int r = 0; r < 8; ++r) acc[r] = 0.f;
        for (int k = 0; k < Kdim; ++k) {
            float wv = W[(size_t)k * Hout + tid];
#pragma unroll
            for (int r = 0; r < 8; ++r) acc[r] += a[r][k] * wv;
        }
        const float bs = bias[tid];
        float scale = 1.f, beta = 0.f;
        if (g) { scale = g[tid] * rsqrtf(1.f + EPSBN); beta = be[tid]; }
        const float f0 = fw0 ? fw0[0] : 0.f;
        for (int r = 0; r < 8; ++r) {
            int row = row0 + r;
            if (row >= N) break;
            float v = acc[r] + bs;
            if (g) v = v * scale + beta;
            if (relu) v = fmaxf(v, 0.f);
            out[(size_t)row * Hout + tid] = v;
            if (hid) hid[(size_t)row * Hout + tid] = f0 * v;
        }
    }
}

// ---------- CSR build (by dst) ----------
__global__ void hist_kernel(const int* __restrict__ dst, int* __restrict__ deg)
{
    int e = blockIdx.x * blockDim.x + threadIdx.x;
    if (e < NEDGES) atomicAdd(&deg[dst[e]], 1);
}

// Single-block exclusive scan over deg[N] -> rowptr[N+1]; cursor[i]=rowptr[i].
// deg aliases cursor (read before overwrite at same index).
__global__ void scan_kernel(int* __restrict__ cursor, int* __restrict__ rowptr)
{
    __shared__ int buf[1024];
    __shared__ int carry;
    if (threadIdx.x == 0) carry = 0;
    __syncthreads();
    for (int base = 0; base < NNODES; base += 1024) {
        int i = base + threadIdx.x;
        int v = (i < NNODES) ? cursor[i] : 0;
        buf[threadIdx.x] = v;
        __syncthreads();
        for (int off = 1; off < 1024; off <<= 1) {
            int t = (threadIdx.x >= off) ? buf[threadIdx.x - off] : 0;
            __syncthreads();
            buf[threadIdx.x] += t;
            __syncthreads();
        }
        int excl = buf[threadIdx.x] - v;
        if (i < NNODES) { rowptr[i] = carry + excl; cursor[i] = carry + excl; }
        __syncthreads();
        if (threadIdx.x == 1023) carry += buf[1023];
        __syncthreads();
    }
    if (threadIdx.x == 0) rowptr[NNODES] = carry;
}

__global__ void fill_kernel(const int* __restrict__ dst, const int* __restrict__ src,
                            const float* __restrict__ w, int* __restrict__ cursor,
                            int* __restrict__ csr_src, float* __restrict__ csr_w)
{
    int e = blockIdx.x * blockDim.x + threadIdx.x;
    if (e >= NEDGES) return;
    int pos = atomicAdd(&cursor[dst[e]], 1);
    csr_src[pos] = src[e];
    csr_w[pos]   = w[e];
}

// ---------- gather SpMM, fused with hid += fw * z ----------
// One 64-lane wave per node; lane owns 2 contiguous cols (float2).
__global__ void spmm_gather(const int* __restrict__ rowptr, const int* __restrict__ csr_src,
                            const float* __restrict__ csr_w, const float* __restrict__ zin,
                            float* __restrict__ zout, float* __restrict__ hid,
                            const float* __restrict__ fwp)
{
    int node = blockIdx.x * (blockDim.x >> 6) + (threadIdx.x >> 6);
    if (node >= NNODES) return;
    int lane = threadIdx.x & 63;
    int beg = rowptr[node], end = rowptr[node + 1];
    float ax = 0.f, ay = 0.f;
    int j = beg;
    for (; j + 1 < end; j += 2) {
        int   s0 = csr_src[j],   s1 = csr_src[j + 1];
        float w0 = csr_w[j],     w1 = csr_w[j + 1];
        const float2 v0 = ((const float2*)(zin + (size_t)s0 * HDIM))[lane];
        const float2 v1 = ((const float2*)(zin + (size_t)s1 * HDIM))[lane];
        ax += w0 * v0.x + w1 * v1.x;
        ay += w0 * v0.y + w1 * v1.y;
    }
    if (j < end) {
        int s = csr_src[j];
        float wt = csr_w[j];
        const float2 v = ((const float2*)(zin + (size_t)s * HDIM))[lane];
        ax += wt * v.x;
        ay += wt * v.y;
    }
    float2* zo = (float2*)(zout + (size_t)node * HDIM);
    float2 o; o.x = ax; o.y = ay;
    zo[lane] = o;
    const float c = fwp[0];
    float2* hp = (float2*)(hid + (size_t)node * HDIM);
    float2 h = hp[lane];
    h.x += c * ax;
    h.y += c * ay;
    hp[lane] = h;
}

// pool[batch[i]] += h[i]
__global__ void pool_kernel(const float* __restrict__ h, const int* __restrict__ batch,
                            float* __restrict__ pool)
{
    unsigned t = blockIdx.x * blockDim.x + threadIdx.x;
    unsigned i = t >> 5;
    if (i >= NNODES) return;
    unsigned lane = t & 31;
    int b = batch[i];
    const float4 v = ((const float4*)(h + (size_t)i * HDIM))[lane];
    float* o = pool + (size_t)b * HDIM + (size_t)lane * 4;
    atomicAdd(o + 0, v.x);
    atomicAdd(o + 1, v.y);
    atomicAdd(o + 2, v.z);
    atomicAdd(o + 3, v.w);
}

extern "C" void kernel_launch(void* const* d_in, const int* in_sizes, int n_in,
                              void* d_out, int out_size, void* d_ws, size_t ws_size,
                              hipStream_t stream)
{
    const float* x     = (const float*)d_in[0];
    const int*   ei    = (const int*)  d_in[1];   // [O,2,E]: [o,0,:]=dst, [o,1,:]=src
    const float* ew    = (const float*)d_in[2];   // [O,E]
    const int*   batch = (const int*)  d_in[3];
    const float* W_in  = (const float*)d_in[4];
    const float* b_in  = (const float*)d_in[5];
    const float* fW    = (const float*)d_in[6];
    const float* W_out = (const float*)d_in[7];
    const float* b_out = (const float*)d_in[8];
    const float* Wn1   = (const float*)d_in[9];
    const float* bn1   = (const float*)d_in[10];
    const float* g1    = (const float*)d_in[11];
    const float* be1   = (const float*)d_in[12];
    const float* Wn2   = (const float*)d_in[13];
    const float* bn2   = (const float*)d_in[14];
    const float* g2    = (const float*)d_in[15];
    const float* be2   = (const float*)d_in[16];
    const float* W1    = (const float*)d_in[17];
    const float* b1    = (const float*)d_in[18];
    const float* W2    = (const float*)d_in[19];
    const float* b2    = (const float*)d_in[20];
    float* out = (float*)d_out;

    const size_t NH = (size_t)NNODES * HDIM;   // 6.4M floats
    float* ws  = (float*)d_ws;
    float* f_A = ws;            // z ping
    float* f_B = ws + NH;       // z pong
    float* f_C = ws + 2 * NH;   // hid o=0
    float* f_D = ws + 3 * NH;   // hid o=1 / next-layer h
    float* f_pl  = ws + 4 * NH;
    float* f_pl2 = f_pl + (size_t)GNUM * HDIM;

    // CSR area (ints/floats) after pools
    int*   ib       = (int*)(f_pl2 + (size_t)GNUM * HDIM);
    int*   rowptr0  = ib;                       // N+1
    int*   cursor0  = rowptr0 + (NNODES + 1);   // N
    int*   rowptr1  = cursor0 + NNODES;         // N+1
    int*   cursor1  = rowptr1 + (NNODES + 1);   // N
    int*   csr_src0 = cursor1 + NNODES;         // E
    int*   csr_src1 = csr_src0 + NEDGES;        // E
    float* csr_w0   = (float*)(csr_src1 + NEDGES); // E
    float* csr_w1   = csr_w0 + NEDGES;             // E

    const int gemm_grid = (NNODES + 7) / 8;
    const int edge_grid = (NEDGES + 255) / 256;
    const int spmm_grid = (NNODES + 3) / 4;     // 4 waves/block

    // ---- build CSR for both orders ----
    for (int o = 0; o < ONUM; ++o) {
        const int* dstp = ei + (size_t)o * 2 * NEDGES;
        const int* srcp = dstp + NEDGES;
        const float* wp = ew + (size_t)o * NEDGES;
        int* cur = (o == 0) ? cursor0 : cursor1;
        int* rp  = (o == 0) ? rowptr0 : rowptr1;
        int* cs  = (o == 0) ? csr_src0 : csr_src1;
        float* cw = (o == 0) ? csr_w0 : csr_w1;
        hipMemsetAsync(cur, 0, NNODES * sizeof(int), stream);
        hist_kernel<<<edge_grid, 256, 0, stream>>>(dstp, cur);
        scan_kernel<<<1, 1024, 0, stream>>>(cur, rp);
        fill_kernel<<<edge_grid, 256, 0, stream>>>(dstp, srcp, wp, cur, cs, cw);
    }

    const float* curH = x;
    for (int l = 0; l < LNUM; ++l) {
        for (int o = 0; o < ONUM; ++o) {
            float* hid = (o == 0) ? f_C : f_D;
            const int lo = l * ONUM + o;
            const int* rp  = (o == 0) ? rowptr0 : rowptr1;
            const int* cs  = (o == 0) ? csr_src0 : csr_src1;
            const float* cw = (o == 0) ? csr_w0 : csr_w1;
            // z = h @ W_in + b_in ; hid = fW[0]*z  (hid may alias curH row-wise)
            gemm_rows<<<gemm_grid, 128, 0, stream>>>(
                curH, nullptr,
                W_in + (size_t)lo * HDIM * HDIM, b_in + (size_t)lo * HDIM,
                nullptr, nullptr, fW + (size_t)lo * (KHOPS + 1),
                f_A, hid, NNODES, HDIM, 0);
            float *za = f_A, *zb = f_B;
            for (int k = 0; k < KHOPS; ++k) {
                spmm_gather<<<spmm_grid, 256, 0, stream>>>(
                    rp, cs, cw, za, zb, hid,
                    fW + (size_t)lo * (KHOPS + 1) + (k + 1));
                float* tmp = za; za = zb; zb = tmp;
            }
        }
        // xc = [hid0|hid1] @ W_out + b_out -> f_A
        gemm_rows<<<gemm_grid, 128, 0, stream>>>(
            f_C, f_D, W_out + (size_t)l * 2 * HDIM * HDIM, b_out + (size_t)l * HDIM,
            nullptr, nullptr, nullptr, f_A, nullptr, NNODES, HDIM, 0);
        // xc = relu(bn(xc @ Wn1 + bn1)) -> f_B
        gemm_rows<<<gemm_grid, 128, 0, stream>>>(
            f_A, nullptr, Wn1 + (size_t)l * HDIM * HDIM, bn1 + (size_t)l * HDIM,
            g1 + (size_t)l * HDIM, be1 + (size_t)l * HDIM, nullptr,
            f_B, nullptr, NNODES, HDIM, 1);
        // h = relu(bn(xc @ Wn2 + bn2)) -> f_D (next curH)
        gemm_rows<<<gemm_grid, 128, 0, stream>>>(
            f_B, nullptr, Wn2 + (size_t)l * HDIM * HDIM, bn2 + (size_t)l * HDIM,
            g2 + (size_t)l * HDIM, be2 + (size_t)l * HDIM, nullptr,
            f_D, nullptr, NNODES, HDIM, 1);
        curH = f_D;
    }

    // global_add_pool
    hipMemsetAsync(f_pl, 0, (size_t)GNUM * HDIM * sizeof(float), stream);
    pool_kernel<<<(NNODES * 32 + 255) / 256, 256, 0, stream>>>(curH, batch, f_pl);
    gemm_rows<<<(GNUM + 7) / 8, 128, 0, stream>>>(
        f_pl, nullptr, W1, b1, nullptr, nullptr, nullptr, f_pl2, nullptr, GNUM, HDIM, 1);
    gemm_rows<<<(GNUM + 7) / 8, 128, 0, stream>>>(
        f_pl2, nullptr, W2, b2, nullptr, nullptr, nullptr, out, nullptr, GNUM, CDIM, 0);
}

// Round 3
// 4317.864 us; speedup vs baseline: 19.7244x; 1.2556x over previous
//
#include <hip/hip_runtime.h>

#define NNODES 50000
#define NEDGES 800000
#define HDIM 128
#define CDIM 10
#define LNUM 3
#define ONUM 2
#define KHOPS 10
#define GNUM 128
#define EPSBN 1e-5f

typedef unsigned int uint;
typedef unsigned short ushort;
typedef __attribute__((ext_vector_type(8))) short bf16x8;
typedef __attribute__((ext_vector_type(4))) float f32x4;

__device__ __forceinline__ ushort f2bf(float f) {
    uint u = __builtin_bit_cast(uint, f);
    uint r = (u + 0x7fffu + ((u >> 16) & 1u)) >> 16;
    return (ushort)r;
}
__device__ __forceinline__ float bf2f_lo(uint u) { return __builtin_bit_cast(float, u << 16); }
__device__ __forceinline__ float bf2f_hi(uint u) { return __builtin_bit_cast(float, u & 0xffff0000u); }

// ---------------- MFMA GEMM ----------------
// out[N,128] = [A0 | A1] @ W + bias  (W given pre-transposed bf16: Wt[n][k], n=128 rows, Kdim cols)
// optional BN (g,be), relu; optional bf16 z output and hid = fw0[0]*out.
// Block: 256 thr (4 waves), 64 rows, full 128 cols, K in chunks of 128.
// In-place safe w.r.t. A0/A1 (rows fully staged to LDS before any global write).
#define KC 128
#define LDA 136  // KC + 8 bf16 pad
__global__ __launch_bounds__(256) void mfma_gemm(
    const float* __restrict__ A0, const float* __restrict__ A1,
    const ushort* __restrict__ Wt, int Kdim,
    const float* __restrict__ bias, const float* __restrict__ g,
    const float* __restrict__ be, const float* __restrict__ fw0,
    float* __restrict__ outf, ushort* __restrict__ outz,
    float* __restrict__ hid, int relu)
{
    __shared__ ushort sA[64 * LDA];
    __shared__ ushort sB[128 * LDA];
    const int row0 = blockIdx.x * 64;
    const int tid  = threadIdx.x;
    const int w    = tid >> 6;
    const int lane = tid & 63;
    const int lr   = lane & 15;
    const int q    = lane >> 4;

    f32x4 acc[8];
#pragma unroll
    for (int nt = 0; nt < 8; ++nt)
#pragma unroll
        for (int j = 0; j < 4; ++j) acc[nt][j] = 0.f;

    const int nch = A1 ? 2 : 1;
    for (int c = 0; c < nch; ++c) {
        const float* Asrc = c ? A1 : A0;
        // stage A chunk: 64 rows x 64 float2 -> bf16 pairs
        for (int idx = tid; idx < 64 * 64; idx += 256) {
            int r = idx >> 6, kp = idx & 63;
            int row = row0 + r;
            float2 v = make_float2(0.f, 0.f);
            if (row < NNODES) v = ((const float2*)(Asrc + (size_t)row * HDIM))[kp];
            uint pv = (uint)f2bf(v.x) | ((uint)f2bf(v.y) << 16);
            ((uint*)(sA + r * LDA))[kp] = pv;
        }
        // stage Wt chunk: 128 rows x 64 uint (already bf16)
        for (int idx = tid; idx < 128 * 64; idx += 256) {
            int n = idx >> 6, kp = idx & 63;
            uint u = ((const uint*)(Wt + (size_t)n * Kdim + c * KC))[kp];
            ((uint*)(sB + n * LDA))[kp] = u;
        }
        __syncthreads();
#pragma unroll
        for (int kt = 0; kt < 4; ++kt) {
            bf16x8 a = *(const bf16x8*)(sA + (16 * w + lr) * LDA + kt * 32 + q * 8);
#pragma unroll
            for (int nt = 0; nt < 8; ++nt) {
                bf16x8 b = *(const bf16x8*)(sB + (nt * 16 + lr) * LDA + kt * 32 + q * 8);
                acc[nt] = __builtin_amdgcn_mfma_f32_16x16x32_bf16(a, b, acc[nt], 0, 0, 0);
            }
        }
        __syncthreads();
    }

    const float f0 = fw0 ? fw0[0] : 0.f;
#pragma unroll
    for (int nt = 0; nt < 8; ++nt) {
        int col = nt * 16 + lr;
        float bs = bias[col];
        float sc = 1.f, bt = 0.f;
        if (g) { sc = g[col] * rsqrtf(1.f + EPSBN); bt = be[col]; }
#pragma unroll
        for (int r = 0; r < 4; ++r) {
            int row = row0 + 16 * w + q * 4 + r;
            if (row >= NNODES) continue;
            float v = acc[nt][r] + bs;
            if (g) v = v * sc + bt;
            if (relu) v = fmaxf(v, 0.f);
            size_t off = (size_t)row * HDIM + col;
            if (outf) outf[off] = v;
            if (outz) outz[off] = f2bf(v);
            if (hid)  hid[off]  = f0 * v;
        }
    }
}

// weight transpose+convert: W[b][k][n] f32 -> Wt[b][n][k] bf16
__global__ void wtrans(const float* __restrict__ W, ushort* __restrict__ Wt, int Kd)
{
    const float* Wm = W + (size_t)blockIdx.x * Kd * HDIM;
    ushort* Wtm = Wt + (size_t)blockIdx.x * Kd * HDIM;
    for (int idx = threadIdx.x; idx < Kd * HDIM; idx += 256) {
        int k = idx >> 7, n = idx & 127;
        Wtm[(size_t)n * Kd + k] = f2bf(Wm[idx]);
    }
}

// small f32 GEMM for the [G,H] tail
__global__ void gemm_rows(const float* __restrict__ A0,
                          const float* __restrict__ W, const float* __restrict__ bias,
                          float* __restrict__ out, int N, int Hout, int relu)
{
    __shared__ float a[8][HDIM];
    const int row0 = blockIdx.x * 8;
    const int tid  = threadIdx.x;
    for (int r = 0; r < 8; ++r) {
        int row = row0 + r;
        a[r][tid] = (row < N) ? A0[(size_t)row * HDIM + tid] : 0.f;
    }
    __syncthreads();
    if (tid < Hout) {
        float acc[8];
#pragma unroll
        for (int r = 0; r < 8; ++r) acc[r] = 0.f;
        for (int k = 0; k < HDIM; ++k) {
            float wv = W[(size_t)k * Hout + tid];
#pragma unroll
            for (int r = 0; r < 8; ++r) acc[r] += a[r][k] * wv;
        }
        const float bs = bias[tid];
        for (int r = 0; r < 8; ++r) {
            int row = row0 + r;
            if (row >= N) break;
            float v = acc[r] + bs;
            if (relu) v = fmaxf(v, 0.f);
            out[(size_t)row * Hout + tid] = v;
        }
    }
}

// ---------- CSR build (by dst) ----------
__global__ void hist_kernel(const int* __restrict__ dst, int* __restrict__ deg)
{
    int e = blockIdx.x * blockDim.x + threadIdx.x;
    if (e < NEDGES) atomicAdd(&deg[dst[e]], 1);
}

// 1024-thread single-block exclusive scan via wave shfl; cursor aliases deg.
__global__ void scan_kernel(int* __restrict__ cursor, int* __restrict__ rowptr)
{
    __shared__ int wsum[16];
    __shared__ int carry;
    const int lane = threadIdx.x & 63, w = threadIdx.x >> 6;
    if (threadIdx.x == 0) carry = 0;
    __syncthreads();
    for (int base = 0; base < NNODES; base += 1024) {
        int i = base + threadIdx.x;
        int v_in = (i < NNODES) ? cursor[i] : 0;
        int v = v_in;
#pragma unroll
        for (int d = 1; d < 64; d <<= 1) {
            int u = __shfl_up(v, d, 64);
            if (lane >= d) v += u;
        }
        if (lane == 63) wsum[w] = v;
        __syncthreads();
        if (w == 0) {
            int s = (lane < 16) ? wsum[lane] : 0;
#pragma unroll
            for (int d = 1; d < 16; d <<= 1) {
                int u = __shfl_up(s, d, 64);
                if (lane >= d) s += u;
            }
            if (lane < 16) wsum[lane] = s;
        }
        __syncthreads();
        int wave_excl = (w == 0) ? 0 : wsum[w - 1];
        int excl = carry + wave_excl + (v - v_in);
        if (i < NNODES) { rowptr[i] = excl; cursor[i] = excl; }
        __syncthreads();
        if (threadIdx.x == 1023) carry += wsum[15];
        __syncthreads();
    }
    if (threadIdx.x == 0) rowptr[NNODES] = carry;
}

__global__ void fill_kernel(const int* __restrict__ dst, const int* __restrict__ src,
                            const float* __restrict__ w, int* __restrict__ cursor,
                            int* __restrict__ csr_src, float* __restrict__ csr_w)
{
    int e = blockIdx.x * blockDim.x + threadIdx.x;
    if (e >= NEDGES) return;
    int pos = atomicAdd(&cursor[dst[e]], 1);
    csr_src[pos] = src[e];
    csr_w[pos]   = w[e];
}

// ---------- gather SpMM on bf16 z, fused hid += fw * z (hid f32) ----------
__global__ void spmm_gather(const int* __restrict__ rowptr, const int* __restrict__ csr_src,
                            const float* __restrict__ csr_w, const ushort* __restrict__ zin,
                            ushort* __restrict__ zout, float* __restrict__ hid,
                            const float* __restrict__ fwp)
{
    int node = blockIdx.x * (blockDim.x >> 6) + (threadIdx.x >> 6);
    if (node >= NNODES) return;
    int lane = threadIdx.x & 63;
    int beg = rowptr[node], end = rowptr[node + 1];
    float ax = 0.f, ay = 0.f;
    int j = beg;
    for (; j + 1 < end; j += 2) {
        int   s0 = csr_src[j],   s1 = csr_src[j + 1];
        float w0 = csr_w[j],     w1 = csr_w[j + 1];
        uint u0 = ((const uint*)(zin + (size_t)s0 * HDIM))[lane];
        uint u1 = ((const uint*)(zin + (size_t)s1 * HDIM))[lane];
        ax += w0 * bf2f_lo(u0) + w1 * bf2f_lo(u1);
        ay += w0 * bf2f_hi(u0) + w1 * bf2f_hi(u1);
    }
    if (j < end) {
        int s = csr_src[j];
        float wt = csr_w[j];
        uint u = ((const uint*)(zin + (size_t)s * HDIM))[lane];
        ax += wt * bf2f_lo(u);
        ay += wt * bf2f_hi(u);
    }
    ((uint*)(zout + (size_t)node * HDIM))[lane] = (uint)f2bf(ax) | ((uint)f2bf(ay) << 16);
    const float c = fwp[0];
    float2* hp = (float2*)(hid + (size_t)node * HDIM);
    float2 h = hp[lane];
    h.x += c * ax;
    h.y += c * ay;
    hp[lane] = h;
}

// ---------- segmented pool (batch sorted), no atomics ----------
__global__ __launch_bounds__(1024) void pool_seg(const float* __restrict__ h,
                                                 const int* __restrict__ batch,
                                                 float* __restrict__ pool)
{
    __shared__ float red[1024];
    const int gph = blockIdx.x;
    const int t  = threadIdx.x & 127;
    const int rr = threadIdx.x >> 7;   // 0..7
    int lo = 0, hi = NNODES;
    while (lo < hi) { int m = (lo + hi) >> 1; if (batch[m] < gph) lo = m + 1; else hi = m; }
    const int beg = lo;
    hi = NNODES;
    while (lo < hi) { int m = (lo + hi) >> 1; if (batch[m] < gph + 1) lo = m + 1; else hi = m; }
    const int end = lo;
    float acc = 0.f;
    for (int i = beg + rr; i < end; i += 8) acc += h[(size_t)i * HDIM + t];
    red[threadIdx.x] = acc;
    __syncthreads();
    if (rr == 0) {
        float s = 0.f;
#pragma unroll
        for (int k = 0; k < 8; ++k) s += red[t + 128 * k];
        pool[(size_t)gph * HDIM + t] = s;
    }
}

extern "C" void kernel_launch(void* const* d_in, const int* in_sizes, int n_in,
                              void* d_out, int out_size, void* d_ws, size_t ws_size,
                              hipStream_t stream)
{
    const float* x     = (const float*)d_in[0];
    const int*   ei    = (const int*)  d_in[1];
    const float* ew    = (const float*)d_in[2];
    const int*   batch = (const int*)  d_in[3];
    const float* W_in  = (const float*)d_in[4];
    const float* b_in  = (const float*)d_in[5];
    const float* fW    = (const float*)d_in[6];
    const float* W_out = (const float*)d_in[7];
    const float* b_out = (const float*)d_in[8];
    const float* Wn1   = (const float*)d_in[9];
    const float* bn1   = (const float*)d_in[10];
    const float* g1    = (const float*)d_in[11];
    const float* be1   = (const float*)d_in[12];
    const float* Wn2   = (const float*)d_in[13];
    const float* bn2   = (const float*)d_in[14];
    const float* g2    = (const float*)d_in[15];
    const float* be2   = (const float*)d_in[16];
    const float* W1    = (const float*)d_in[17];
    const float* b1    = (const float*)d_in[18];
    const float* W2    = (const float*)d_in[19];
    const float* b2    = (const float*)d_in[20];
    float* out = (float*)d_out;

    const size_t NH = (size_t)NNODES * HDIM;
    float* ws  = (float*)d_ws;
    float*  f_A  = ws;                  // h/hid buffer A
    float*  f_B  = ws + NH;             // h/hid buffer B
    ushort* zA   = (ushort*)(ws + 2 * NH);            // NH bf16
    ushort* zB   = zA + NH;                           // NH bf16
    float*  f_pl  = (float*)(zB + NH);
    float*  f_pl2 = f_pl + (size_t)GNUM * HDIM;

    // pre-transposed bf16 weights
    ushort* Wt_in  = (ushort*)(f_pl2 + (size_t)GNUM * HDIM);   // 6 * 128*128
    ushort* Wt_out = Wt_in  + (size_t)6 * HDIM * HDIM;         // 3 * 256*128
    ushort* Wt_n1  = Wt_out + (size_t)3 * 2 * HDIM * HDIM;     // 3 * 128*128
    ushort* Wt_n2  = Wt_n1  + (size_t)3 * HDIM * HDIM;         // 3 * 128*128

    int*   ib       = (int*)(Wt_n2 + (size_t)3 * HDIM * HDIM);
    int*   rowptr0  = ib;
    int*   cursor0  = rowptr0 + (NNODES + 1);
    int*   rowptr1  = cursor0 + NNODES;
    int*   cursor1  = rowptr1 + (NNODES + 1);
    int*   csr_src0 = cursor1 + NNODES;
    int*   csr_src1 = csr_src0 + NEDGES;
    float* csr_w0   = (float*)(csr_src1 + NEDGES);
    float* csr_w1   = csr_w0 + NEDGES;

    const int gemm_grid = (NNODES + 63) / 64;   // 782
    const int edge_grid = (NEDGES + 255) / 256;
    const int spmm_grid = (NNODES + 3) / 4;

    // ---- transpose weights to bf16 n-major ----
    wtrans<<<6, 256, 0, stream>>>(W_in,  Wt_in,  HDIM);
    wtrans<<<3, 256, 0, stream>>>(W_out, Wt_out, 2 * HDIM);
    wtrans<<<3, 256, 0, stream>>>(Wn1,   Wt_n1,  HDIM);
    wtrans<<<3, 256, 0, stream>>>(Wn2,   Wt_n2,  HDIM);

    // ---- build CSR for both orders ----
    for (int o = 0; o < ONUM; ++o) {
        const int* dstp = ei + (size_t)o * 2 * NEDGES;
        const int* srcp = dstp + NEDGES;
        const float* wp = ew + (size_t)o * NEDGES;
        int* cur = (o == 0) ? cursor0 : cursor1;
        int* rp  = (o == 0) ? rowptr0 : rowptr1;
        int* cs  = (o == 0) ? csr_src0 : csr_src1;
        float* cw = (o == 0) ? csr_w0 : csr_w1;
        hipMemsetAsync(cur, 0, NNODES * sizeof(int), stream);
        hist_kernel<<<edge_grid, 256, 0, stream>>>(dstp, cur);
        scan_kernel<<<1, 1024, 0, stream>>>(cur, rp);
        fill_kernel<<<edge_grid, 256, 0, stream>>>(dstp, srcp, wp, cur, cs, cw);
    }

    const float* curH = x;
    for (int l = 0; l < LNUM; ++l) {
        // pick buffers: h0 != curH, h1 may be curH (in-place safe), except l=0
        float* h0 = (curH == (const float*)f_A) ? f_B : f_A;
        float* h1 = (l == 0) ? f_B : (float*)curH;
        for (int o = 0; o < ONUM; ++o) {
            float* hid = (o == 0) ? h0 : h1;
            const int lo = l * ONUM + o;
            const int* rp  = (o == 0) ? rowptr0 : rowptr1;
            const int* cs  = (o == 0) ? csr_src0 : csr_src1;
            const float* cw = (o == 0) ? csr_w0 : csr_w1;
            // z = h @ W_in + b_in (bf16 z) ; hid = fW[0]*z (f32)
            mfma_gemm<<<gemm_grid, 256, 0, stream>>>(
                curH, nullptr, Wt_in + (size_t)lo * HDIM * HDIM, HDIM,
                b_in + (size_t)lo * HDIM, nullptr, nullptr,
                fW + (size_t)lo * (KHOPS + 1),
                nullptr, zA, hid, 0);
            ushort *za = zA, *zb = zB;
            for (int k = 0; k < KHOPS; ++k) {
                spmm_gather<<<spmm_grid, 256, 0, stream>>>(
                    rp, cs, cw, za, zb, hid,
                    fW + (size_t)lo * (KHOPS + 1) + (k + 1));
                ushort* tmp = za; za = zb; zb = tmp;
            }
        }
        // xc = [h0|h1] @ W_out + b_out -> h0 (in-place safe)
        mfma_gemm<<<gemm_grid, 256, 0, stream>>>(
            h0, h1, Wt_out + (size_t)l * 2 * HDIM * HDIM, 2 * HDIM,
            b_out + (size_t)l * HDIM, nullptr, nullptr, nullptr,
            h0, nullptr, nullptr, 0);
        // xc = relu(bn(xc @ Wn1 + bn1)) -> h1
        mfma_gemm<<<gemm_grid, 256, 0, stream>>>(
            h0, nullptr, Wt_n1 + (size_t)l * HDIM * HDIM, HDIM,
            bn1 + (size_t)l * HDIM, g1 + (size_t)l * HDIM, be1 + (size_t)l * HDIM,
            nullptr, h1, nullptr, nullptr, 1);
        // h = relu(bn(xc @ Wn2 + bn2)) -> h0 (next curH)
        mfma_gemm<<<gemm_grid, 256, 0, stream>>>(
            h1, nullptr, Wt_n2 + (size_t)l * HDIM * HDIM, HDIM,
            bn2 + (size_t)l * HDIM, g2 + (size_t)l * HDIM, be2 + (size_t)l * HDIM,
            nullptr, h0, nullptr, nullptr, 1);
        curH = h0;
    }

    // global_add_pool (batch sorted -> segment reduce)
    pool_seg<<<GNUM, 1024, 0, stream>>>(curH, batch, f_pl);
    gemm_rows<<<(GNUM + 7) / 8, 128, 0, stream>>>(f_pl,  W1, b1, f_pl2, GNUM, HDIM, 1);
    gemm_rows<<<(GNUM + 7) / 8, 128, 0, stream>>>(f_pl2, W2, b2, out,   GNUM, CDIM, 0);
}

// Round 4
// 2807.528 us; speedup vs baseline: 30.3353x; 1.5380x over previous
//
#include <hip/hip_runtime.h>

#define NNODES 50000
#define NEDGES 800000
#define HDIM 128
#define CDIM 10
#define LNUM 3
#define ONUM 2
#define KHOPS 10
#define GNUM 128
#define EPSBN 1e-5f

typedef unsigned int uint;
typedef unsigned short ushort;
typedef __attribute__((ext_vector_type(8))) short bf16x8;
typedef __attribute__((ext_vector_type(4))) float f32x4;

__device__ __forceinline__ ushort f2bf(float f) {
    uint u = __builtin_bit_cast(uint, f);
    uint r = (u + 0x7fffu + ((u >> 16) & 1u)) >> 16;
    return (ushort)r;
}
__device__ __forceinline__ float bf2f_lo(uint u) { return __builtin_bit_cast(float, u << 16); }
__device__ __forceinline__ float bf2f_hi(uint u) { return __builtin_bit_cast(float, u & 0xffff0000u); }

// ---------------- MFMA GEMM ----------------
// out[N,128] = [A0 | A1] @ W + bias  (Wt pre-transposed bf16 [n][k])
// optional BN (g,be), relu; optional bf16 z output and hid = fw0[0]*out.
// 256 thr / 64 rows / 128 cols; in-place safe (block reads only its own rows).
#define KC 128
#define LDA 136
__global__ __launch_bounds__(256) void mfma_gemm(
    const float* __restrict__ A0, const float* __restrict__ A1,
    const ushort* __restrict__ Wt, int Kdim,
    const float* __restrict__ bias, const float* __restrict__ g,
    const float* __restrict__ be, const float* __restrict__ fw0,
    float* __restrict__ outf, ushort* __restrict__ outz,
    float* __restrict__ hid, int relu)
{
    __shared__ ushort sA[64 * LDA];
    __shared__ ushort sB[128 * LDA];
    const int row0 = blockIdx.x * 64;
    const int tid  = threadIdx.x;
    const int w    = tid >> 6;
    const int lane = tid & 63;
    const int lr   = lane & 15;
    const int q    = lane >> 4;

    f32x4 acc[8];
#pragma unroll
    for (int nt = 0; nt < 8; ++nt)
#pragma unroll
        for (int j = 0; j < 4; ++j) acc[nt][j] = 0.f;

    const int nch = A1 ? 2 : 1;
    for (int c = 0; c < nch; ++c) {
        const float* Asrc = c ? A1 : A0;
        for (int idx = tid; idx < 64 * 64; idx += 256) {
            int r = idx >> 6, kp = idx & 63;
            int row = row0 + r;
            float2 v = make_float2(0.f, 0.f);
            if (row < NNODES) v = ((const float2*)(Asrc + (size_t)row * HDIM))[kp];
            uint pv = (uint)f2bf(v.x) | ((uint)f2bf(v.y) << 16);
            ((uint*)(sA + r * LDA))[kp] = pv;
        }
        for (int idx = tid; idx < 128 * 64; idx += 256) {
            int n = idx >> 6, kp = idx & 63;
            uint u = ((const uint*)(Wt + (size_t)n * Kdim + c * KC))[kp];
            ((uint*)(sB + n * LDA))[kp] = u;
        }
        __syncthreads();
#pragma unroll
        for (int kt = 0; kt < 4; ++kt) {
            bf16x8 a = *(const bf16x8*)(sA + (16 * w + lr) * LDA + kt * 32 + q * 8);
#pragma unroll
            for (int nt = 0; nt < 8; ++nt) {
                bf16x8 b = *(const bf16x8*)(sB + (nt * 16 + lr) * LDA + kt * 32 + q * 8);
                acc[nt] = __builtin_amdgcn_mfma_f32_16x16x32_bf16(a, b, acc[nt], 0, 0, 0);
            }
        }
        __syncthreads();
    }

    const float f0 = fw0 ? fw0[0] : 0.f;
#pragma unroll
    for (int nt = 0; nt < 8; ++nt) {
        int col = nt * 16 + lr;
        float bs = bias[col];
        float sc = 1.f, bt = 0.f;
        if (g) { sc = g[col] * rsqrtf(1.f + EPSBN); bt = be[col]; }
#pragma unroll
        for (int r = 0; r < 4; ++r) {
            int row = row0 + 16 * w + q * 4 + r;
            if (row >= NNODES) continue;
            float v = acc[nt][r] + bs;
            if (g) v = v * sc + bt;
            if (relu) v = fmaxf(v, 0.f);
            size_t off = (size_t)row * HDIM + col;
            if (outf) outf[off] = v;
            if (outz) outz[off] = f2bf(v);
            if (hid)  hid[off]  = f0 * v;
        }
    }
}

// all weight transposes in one launch: blocks 0-5 W_in, 6-8 W_out, 9-11 Wn1, 12-14 Wn2
__global__ void wtrans_all(const float* __restrict__ W_in, const float* __restrict__ W_out,
                           const float* __restrict__ Wn1, const float* __restrict__ Wn2,
                           ushort* __restrict__ Wt_in, ushort* __restrict__ Wt_out,
                           ushort* __restrict__ Wt_n1, ushort* __restrict__ Wt_n2)
{
    int b = blockIdx.x;
    const float* W; ushort* Wt; int Kd;
    if (b < 6)       { Kd = HDIM;     W = W_in  + (size_t)b * Kd * HDIM;       Wt = Wt_in  + (size_t)b * Kd * HDIM; }
    else if (b < 9)  { Kd = 2 * HDIM; W = W_out + (size_t)(b - 6) * Kd * HDIM; Wt = Wt_out + (size_t)(b - 6) * Kd * HDIM; }
    else if (b < 12) { Kd = HDIM;     W = Wn1   + (size_t)(b - 9) * Kd * HDIM; Wt = Wt_n1  + (size_t)(b - 9) * Kd * HDIM; }
    else             { Kd = HDIM;     W = Wn2   + (size_t)(b - 12) * Kd * HDIM; Wt = Wt_n2 + (size_t)(b - 12) * Kd * HDIM; }
    for (int idx = threadIdx.x; idx < Kd * HDIM; idx += 512) {
        int k = idx >> 7, n = idx & 127;
        Wt[(size_t)n * Kd + k] = f2bf(W[idx]);
    }
}

// small f32 GEMM for the [G,H] tail
__global__ void gemm_rows(const float* __restrict__ A0,
                          const float* __restrict__ W, const float* __restrict__ bias,
                          float* __restrict__ out, int N, int Hout, int relu)
{
    __shared__ float a[8][HDIM];
    const int row0 = blockIdx.x * 8;
    const int tid  = threadIdx.x;
    for (int r = 0; r < 8; ++r) {
        int row = row0 + r;
        a[r][tid] = (row < N) ? A0[(size_t)row * HDIM + tid] : 0.f;
    }
    __syncthreads();
    if (tid < Hout) {
        float acc[8];
#pragma unroll
        for (int r = 0; r < 8; ++r) acc[r] = 0.f;
        for (int k = 0; k < HDIM; ++k) {
            float wv = W[(size_t)k * Hout + tid];
#pragma unroll
            for (int r = 0; r < 8; ++r) acc[r] += a[r][k] * wv;
        }
        const float bs = bias[tid];
        for (int r = 0; r < 8; ++r) {
            int row = row0 + r;
            if (row >= N) break;
            float v = acc[r] + bs;
            if (relu) v = fmaxf(v, 0.f);
            out[(size_t)row * Hout + tid] = v;
        }
    }
}

// ---------- CSR build (by dst), both orders per launch ----------
__global__ void hist2(const int* __restrict__ ei, int* __restrict__ cur0, int* __restrict__ cur1)
{
    int e = blockIdx.x * blockDim.x + threadIdx.x;
    if (e >= NEDGES) return;
    int o = blockIdx.y;
    const int* dst = ei + (size_t)o * 2 * NEDGES;
    atomicAdd((o ? cur1 : cur0) + dst[e], 1);
}

// two-order exclusive scan, 4 elems/thread; cursor gets rowptr copy.
__global__ __launch_bounds__(1024) void scan2(int* __restrict__ cur0, int* __restrict__ rp0,
                                              int* __restrict__ cur1, int* __restrict__ rp1)
{
    int* cursor = blockIdx.x ? cur1 : cur0;
    int* rowptr = blockIdx.x ? rp1 : rp0;
    __shared__ int wsum[16];
    __shared__ int carry;
    const int lane = threadIdx.x & 63, w = threadIdx.x >> 6;
    if (threadIdx.x == 0) carry = 0;
    __syncthreads();
    for (int base = 0; base < NNODES; base += 4096) {
        int i4 = base + threadIdx.x * 4;
        int4 v = make_int4(0, 0, 0, 0);
        if (i4 + 3 < NNODES) v = *(const int4*)(cursor + i4);
        int s0 = v.x, s1 = s0 + v.y, s2 = s1 + v.z, s3 = s2 + v.w;
        int q = s3;
#pragma unroll
        for (int d = 1; d < 64; d <<= 1) {
            int u = __shfl_up(q, d, 64);
            if (lane >= d) q += u;
        }
        if (lane == 63) wsum[w] = q;
        __syncthreads();
        if (w == 0) {
            int s = (lane < 16) ? wsum[lane] : 0;
#pragma unroll
            for (int d = 1; d < 16; d <<= 1) {
                int u = __shfl_up(s, d, 64);
                if (lane >= d) s += u;
            }
            if (lane < 16) wsum[lane] = s;
        }
        __syncthreads();
        int excl = carry + ((w > 0) ? wsum[w - 1] : 0) + (q - s3);
        if (i4 + 3 < NNODES) {
            int4 o4 = make_int4(excl, excl + s0, excl + s1, excl + s2);
            *(int4*)(rowptr + i4) = o4;
            *(int4*)(cursor + i4) = o4;
        }
        __syncthreads();
        if (threadIdx.x == 1023) carry += wsum[15];
        __syncthreads();
    }
    if (threadIdx.x == 0) rowptr[NNODES] = carry;
}

__global__ void fill2(const int* __restrict__ ei, const float* __restrict__ ew,
                      int* __restrict__ cur0, int* __restrict__ cur1,
                      int2* __restrict__ c0, int2* __restrict__ c1)
{
    int e = blockIdx.x * blockDim.x + threadIdx.x;
    if (e >= NEDGES) return;
    int o = blockIdx.y;
    const int* dst = ei + (size_t)o * 2 * NEDGES;
    const int* src = dst + NEDGES;
    const float* wp = ew + (size_t)o * NEDGES;
    int pos = atomicAdd((o ? cur1 : cur0) + dst[e], 1);
    (o ? c1 : c0)[pos] = make_int2(src[e], __builtin_bit_cast(int, wp[e]));
}

// ---------- merged two-order gather SpMM ----------
// grid (ceil(N/4), 2). Even hops (do_hid) also: hid += fwp[0]*zin[node] + fwp[1]*znew.
__global__ void spmm2(const int* __restrict__ rp0, const int2* __restrict__ csr0,
                      const int* __restrict__ rp1, const int2* __restrict__ csr1,
                      const ushort* __restrict__ zin0, ushort* __restrict__ zout0,
                      const ushort* __restrict__ zin1, ushort* __restrict__ zout1,
                      float* __restrict__ hid0, float* __restrict__ hid1,
                      const float* __restrict__ fw0p, const float* __restrict__ fw1p,
                      int do_hid)
{
    int node = blockIdx.x * 4 + (threadIdx.x >> 6);
    if (node >= NNODES) return;
    const int o = blockIdx.y;
    const int lane = threadIdx.x & 63;
    const int*  rp  = o ? rp1 : rp0;
    const int2* csr = o ? csr1 : csr0;
    const ushort* zin = o ? zin1 : zin0;
    ushort* zout = o ? zout1 : zout0;
    float* hid = o ? hid1 : hid0;
    const float* fwp = o ? fw1p : fw0p;

    int beg = __builtin_amdgcn_readfirstlane(rp[node]);
    int end = __builtin_amdgcn_readfirstlane(rp[node + 1]);
    float ax = 0.f, ay = 0.f;
    int j = beg;
    for (; j + 3 < end; j += 4) {
        int2 e0 = csr[j], e1 = csr[j + 1], e2 = csr[j + 2], e3 = csr[j + 3];
        uint u0 = ((const uint*)(zin + (size_t)e0.x * HDIM))[lane];
        uint u1 = ((const uint*)(zin + (size_t)e1.x * HDIM))[lane];
        uint u2 = ((const uint*)(zin + (size_t)e2.x * HDIM))[lane];
        uint u3 = ((const uint*)(zin + (size_t)e3.x * HDIM))[lane];
        float w0 = __builtin_bit_cast(float, e0.y), w1 = __builtin_bit_cast(float, e1.y);
        float w2 = __builtin_bit_cast(float, e2.y), w3 = __builtin_bit_cast(float, e3.y);
        ax += w0 * bf2f_lo(u0) + w1 * bf2f_lo(u1) + w2 * bf2f_lo(u2) + w3 * bf2f_lo(u3);
        ay += w0 * bf2f_hi(u0) + w1 * bf2f_hi(u1) + w2 * bf2f_hi(u2) + w3 * bf2f_hi(u3);
    }
    for (; j < end; ++j) {
        int2 e = csr[j];
        uint u = ((const uint*)(zin + (size_t)e.x * HDIM))[lane];
        float wt = __builtin_bit_cast(float, e.y);
        ax += wt * bf2f_lo(u);
        ay += wt * bf2f_hi(u);
    }
    ((uint*)(zout + (size_t)node * HDIM))[lane] = (uint)f2bf(ax) | ((uint)f2bf(ay) << 16);
    if (do_hid) {
        uint up = ((const uint*)(zin + (size_t)node * HDIM))[lane];
        const float c0 = fwp[0], c1 = fwp[1];
        float2* hp = (float2*)(hid + (size_t)node * HDIM);
        float2 h = hp[lane];
        h.x += c0 * bf2f_lo(up) + c1 * ax;
        h.y += c0 * bf2f_hi(up) + c1 * ay;
        hp[lane] = h;
    }
}

// ---------- segmented pool (batch sorted), no atomics ----------
__global__ __launch_bounds__(1024) void pool_seg(const float* __restrict__ h,
                                                 const int* __restrict__ batch,
                                                 float* __restrict__ pool)
{
    __shared__ float red[1024];
    const int gph = blockIdx.x;
    const int t  = threadIdx.x & 127;
    const int rr = threadIdx.x >> 7;
    int lo = 0, hi = NNODES;
    while (lo < hi) { int m = (lo + hi) >> 1; if (batch[m] < gph) lo = m + 1; else hi = m; }
    const int beg = lo;
    hi = NNODES;
    while (lo < hi) { int m = (lo + hi) >> 1; if (batch[m] < gph + 1) lo = m + 1; else hi = m; }
    const int end = lo;
    float acc = 0.f;
    for (int i = beg + rr; i < end; i += 8) acc += h[(size_t)i * HDIM + t];
    red[threadIdx.x] = acc;
    __syncthreads();
    if (rr == 0) {
        float s = 0.f;
#pragma unroll
        for (int k = 0; k < 8; ++k) s += red[t + 128 * k];
        pool[(size_t)gph * HDIM + t] = s;
    }
}

extern "C" void kernel_launch(void* const* d_in, const int* in_sizes, int n_in,
                              void* d_out, int out_size, void* d_ws, size_t ws_size,
                              hipStream_t stream)
{
    const float* x     = (const float*)d_in[0];
    const int*   ei    = (const int*)  d_in[1];
    const float* ew    = (const float*)d_in[2];
    const int*   batch = (const int*)  d_in[3];
    const float* W_in  = (const float*)d_in[4];
    const float* b_in  = (const float*)d_in[5];
    const float* fW    = (const float*)d_in[6];
    const float* W_out = (const float*)d_in[7];
    const float* b_out = (const float*)d_in[8];
    const float* Wn1   = (const float*)d_in[9];
    const float* bn1   = (const float*)d_in[10];
    const float* g1    = (const float*)d_in[11];
    const float* be1   = (const float*)d_in[12];
    const float* Wn2   = (const float*)d_in[13];
    const float* bn2   = (const float*)d_in[14];
    const float* g2    = (const float*)d_in[15];
    const float* be2   = (const float*)d_in[16];
    const float* W1    = (const float*)d_in[17];
    const float* b1    = (const float*)d_in[18];
    const float* W2    = (const float*)d_in[19];
    const float* b2    = (const float*)d_in[20];
    float* out = (float*)d_out;

    const size_t NH = (size_t)NNODES * HDIM;
    float* ws  = (float*)d_ws;
    float*  f_A = ws;
    float*  f_B = ws + NH;
    ushort* z0A = (ushort*)(ws + 2 * NH);
    ushort* z0B = z0A + NH;
    ushort* z1A = z0B + NH;
    ushort* z1B = z1A + NH;
    float*  f_pl  = (float*)(z1B + NH);
    float*  f_pl2 = f_pl + (size_t)GNUM * HDIM;

    ushort* Wt_in  = (ushort*)(f_pl2 + (size_t)GNUM * HDIM);
    ushort* Wt_out = Wt_in  + (size_t)6 * HDIM * HDIM;
    ushort* Wt_n1  = Wt_out + (size_t)3 * 2 * HDIM * HDIM;
    ushort* Wt_n2  = Wt_n1  + (size_t)3 * HDIM * HDIM;

    int*  rowptr0 = (int*)(Wt_n2 + (size_t)3 * HDIM * HDIM);
    int*  rowptr1 = rowptr0 + (NNODES + 1);
    int*  cursor0 = rowptr1 + (NNODES + 1);
    int*  cursor1 = cursor0 + NNODES;
    int2* csr0    = (int2*)(cursor1 + NNODES);
    int2* csr1    = csr0 + NEDGES;

    const int gemm_grid = (NNODES + 63) / 64;
    const int edge_grid = (NEDGES + 255) / 256;
    const dim3 spmm_grid((NNODES + 3) / 4, 2);

    wtrans_all<<<15, 512, 0, stream>>>(W_in, W_out, Wn1, Wn2, Wt_in, Wt_out, Wt_n1, Wt_n2);

    hipMemsetAsync(cursor0, 0, 2 * NNODES * sizeof(int), stream);
    hist2<<<dim3(edge_grid, 2), 256, 0, stream>>>(ei, cursor0, cursor1);
    scan2<<<2, 1024, 0, stream>>>(cursor0, rowptr0, cursor1, rowptr1);
    fill2<<<dim3(edge_grid, 2), 256, 0, stream>>>(ei, ew, cursor0, cursor1, csr0, csr1);

    const float* curH = x;
    for (int l = 0; l < LNUM; ++l) {
        float* h0 = (curH == (const float*)f_A) ? f_B : f_A;
        float* h1 = (l == 0) ? f_B : (float*)curH;
        const int lo0 = l * ONUM, lo1 = lo0 + 1;
        // z0 = h @ W_in[lo] + b_in (bf16) ; hid = fW[0]*z0
        mfma_gemm<<<gemm_grid, 256, 0, stream>>>(
            curH, nullptr, Wt_in + (size_t)lo0 * HDIM * HDIM, HDIM,
            b_in + (size_t)lo0 * HDIM, nullptr, nullptr,
            fW + (size_t)lo0 * (KHOPS + 1), nullptr, z0A, h0, 0);
        mfma_gemm<<<gemm_grid, 256, 0, stream>>>(
            curH, nullptr, Wt_in + (size_t)lo1 * HDIM * HDIM, HDIM,
            b_in + (size_t)lo1 * HDIM, nullptr, nullptr,
            fW + (size_t)lo1 * (KHOPS + 1), nullptr, z1A, h1, 0);

        ushort *pa0 = z0A, *pb0 = z0B, *pa1 = z1A, *pb1 = z1B;
        for (int k = 1; k <= KHOPS; ++k) {
            spmm2<<<spmm_grid, 256, 0, stream>>>(
                rowptr0, csr0, rowptr1, csr1, pa0, pb0, pa1, pb1, h0, h1,
                fW + (size_t)lo0 * (KHOPS + 1) + (k - 1),
                fW + (size_t)lo1 * (KHOPS + 1) + (k - 1),
                (k & 1) == 0);
            ushort* t;
            t = pa0; pa0 = pb0; pb0 = t;
            t = pa1; pa1 = pb1; pb1 = t;
        }
        // xc = [h0|h1] @ W_out + b_out -> h0
        mfma_gemm<<<gemm_grid, 256, 0, stream>>>(
            h0, h1, Wt_out + (size_t)l * 2 * HDIM * HDIM, 2 * HDIM,
            b_out + (size_t)l * HDIM, nullptr, nullptr, nullptr,
            h0, nullptr, nullptr, 0);
        // xc = relu(bn(xc @ Wn1 + bn1)) -> h1
        mfma_gemm<<<gemm_grid, 256, 0, stream>>>(
            h0, nullptr, Wt_n1 + (size_t)l * HDIM * HDIM, HDIM,
            bn1 + (size_t)l * HDIM, g1 + (size_t)l * HDIM, be1 + (size_t)l * HDIM,
            nullptr, h1, nullptr, nullptr, 1);
        // h = relu(bn(xc @ Wn2 + bn2)) -> h0
        mfma_gemm<<<gemm_grid, 256, 0, stream>>>(
            h1, nullptr, Wt_n2 + (size_t)l * HDIM * HDIM, HDIM,
            bn2 + (size_t)l * HDIM, g2 + (size_t)l * HDIM, be2 + (size_t)l * HDIM,
            nullptr, h0, nullptr, nullptr, 1);
        curH = h0;
    }

    pool_seg<<<GNUM, 1024, 0, stream>>>(curH, batch, f_pl);
    gemm_rows<<<(GNUM + 7) / 8, 128, 0, stream>>>(f_pl,  W1, b1, f_pl2, GNUM, HDIM, 1);
    gemm_rows<<<(GNUM + 7) / 8, 128, 0, stream>>>(f_pl2, W2, b2, out,   GNUM, CDIM, 0);
}